// Round 3
// baseline (609.178 us; speedup 1.0000x reference)
//
#include <hip/hip_runtime.h>
#include <hip/hip_bf16.h>

#define N 8192
#define FIN 256
#define HD 256
#define LEAKY 0.2f

typedef short sh8 __attribute__((ext_vector_type(8)));   // bf16x8 MFMA fragment
typedef float f32x4 __attribute__((ext_vector_type(4)));
typedef int   i32x4 __attribute__((ext_vector_type(4)));

__device__ __forceinline__ int pack2bf(float a, float b){
  __hip_bfloat162 t = __float22bfloat162_rn(make_float2(a, b));
  union { __hip_bfloat162 h; int i; } u;
  u.h = t;
  return u.i;
}

__device__ __forceinline__ unsigned bf16hi_rne(float v){
  unsigned u = __float_as_uint(v);
  u += 0x7FFFu + ((u >> 16) & 1u);
  return u >> 16;
}

// ---------------- K0: W (256x256 f32, [k][c]) -> Wt (bf16, [c][k]) ----------------
__global__ void k_wt(const float* __restrict__ W, __hip_bfloat16* __restrict__ Wt){
  __shared__ float t[16][17];
  int tx = threadIdx.x, ty = threadIdx.y;
  int bx = blockIdx.x*16, by = blockIdx.y*16;
  t[ty][tx] = W[(by+ty)*HD + (bx+tx)];
  __syncthreads();
  Wt[(bx+ty)*FIN + (by+tx)] = __float2bfloat16(t[tx][ty]);
}

// ---------------- K1: h_t[c][n] = sum_k W[k][c] * x[n][k]  (bf16 out) --------------
// Fused epilogue: El=exp(sl), El2=exp(0.2*sl) (fp32, i-side) and EE[h][j] =
// packed (bf16(exp(sr)) | bf16(exp(0.2*sr))<<16) (j-side).
__global__ __launch_bounds__(256, 2) void k_h(
    const float* __restrict__ x, const __hip_bfloat16* __restrict__ Wt,
    const float* __restrict__ a_l, const float* __restrict__ a_r,
    __hip_bfloat16* __restrict__ ht, float* __restrict__ El, float* __restrict__ El2,
    unsigned* __restrict__ ee)
{
  const int lane = threadIdx.x & 63;
  const int w = threadIdx.x >> 6;      // c-group == head
  const int r0 = lane & 15, q = lane >> 4;
  const int c0 = w*64;
  const int n0 = blockIdx.x*32;

  f32x4 acc[4][2];
  #pragma unroll
  for (int m = 0; m < 4; ++m)
    #pragma unroll
    for (int nt = 0; nt < 2; ++nt)
      acc[m][nt] = (f32x4){0.f, 0.f, 0.f, 0.f};

  for (int kb = 0; kb < 8; ++kb){
    const int k = kb*32 + q*8;
    sh8 af[4];
    #pragma unroll
    for (int m = 0; m < 4; ++m)
      af[m] = *(const sh8*)(Wt + (c0 + m*16 + r0)*FIN + k);
    #pragma unroll
    for (int nt = 0; nt < 2; ++nt){
      const float* xp = x + (n0 + nt*16 + r0)*FIN + k;
      f32x4 xl = *(const f32x4*)xp;
      f32x4 xh = *(const f32x4*)(xp + 4);
      union { sh8 s; int i[4]; } bx;
      bx.i[0] = pack2bf(xl[0], xl[1]);
      bx.i[1] = pack2bf(xl[2], xl[3]);
      bx.i[2] = pack2bf(xh[0], xh[1]);
      bx.i[3] = pack2bf(xh[2], xh[3]);
      #pragma unroll
      for (int m = 0; m < 4; ++m)
        acc[m][nt] = __builtin_amdgcn_mfma_f32_16x16x32_bf16(af[m], bx.s, acc[m][nt], 0, 0, 0);
    }
  }

  // epilogue: store h_t (bf16) + fused scores
  float pl[2] = {0.f, 0.f}, pr[2] = {0.f, 0.f};
  #pragma unroll
  for (int m = 0; m < 4; ++m){
    #pragma unroll
    for (int reg = 0; reg < 4; ++reg){
      const int c = c0 + m*16 + q*4 + reg;      // C row = q*4+reg
      const float alv = a_l[c], arv = a_r[c];
      #pragma unroll
      for (int nt = 0; nt < 2; ++nt){
        float v = acc[m][nt][reg];
        ht[(size_t)c*N + (n0 + nt*16 + r0)] = __float2bfloat16(v);  // C col = r0
        pl[nt] += v*alv;
        pr[nt] += v*arv;
      }
    }
  }
  #pragma unroll
  for (int nt = 0; nt < 2; ++nt){
    pl[nt] += __shfl_xor(pl[nt], 16); pl[nt] += __shfl_xor(pl[nt], 32);
    pr[nt] += __shfl_xor(pr[nt], 16); pr[nt] += __shfl_xor(pr[nt], 32);
  }
  if (lane < 16){
    #pragma unroll
    for (int nt = 0; nt < 2; ++nt){
      const int n = n0 + nt*16 + r0;
      const float l = pl[nt], r = pr[nt];
      El [w*N + n] = __expf(l);
      El2[w*N + n] = __expf(LEAKY*l);
      float er  = __expf(r);
      float er2 = __expf(LEAKY*r);
      ee[w*N + n] = bf16hi_rne(er) | (bf16hi_rne(er2) << 16);
    }
  }
}

// ---------------- K_bits: adj (N*N int32) -> bitmask u64[row][N/64], eye OR'd in ---
__global__ __launch_bounds__(256) void k_bits(const int* __restrict__ adj,
                                              unsigned long long* __restrict__ bits)
{
  const int lane = threadIdx.x & 63;
  const int wid = (blockIdx.x*256 + threadIdx.x) >> 6;   // global wave id
  const int nw = (gridDim.x*256) >> 6;
  const int total = (N/64)*N;                            // row-major: idx = r*128 + c
  for (int idx = wid; idx < total; idx += nw){
    const int r = idx >> 7, c = idx & 127;
    int av = __builtin_nontemporal_load(adj + (size_t)r*N + c*64 + lane);
    unsigned long long b = __ballot(av != 0);
    if (c == (r >> 6)) b |= 1ull << (r & 63);            // + eye
    if (lane == 0) bits[idx] = b;
  }
}

// ---------------- K2: masked-softmax numerator/denominator partials ----------------
struct Frag {
  unsigned bw[2];
  i32x4 ee2[2];
  sh8 hf[4];
};

__device__ __forceinline__ void ld_frag(Frag& f, int t,
    const unsigned* __restrict__ bp0, const unsigned* __restrict__ bp1,
    const unsigned* __restrict__ eeh, const __hip_bfloat16* __restrict__ htb,
    int joff)
{
  const int jl = joff + t*32;
  f.bw[0] = bp0[t]; f.bw[1] = bp1[t];
  f.ee2[0] = *(const i32x4*)(eeh + jl);
  f.ee2[1] = *(const i32x4*)(eeh + jl + 4);
  #pragma unroll
  for (int d = 0; d < 4; ++d)
    f.hf[d] = *(const sh8*)(htb + (size_t)(d*16)*N + jl);
}

__device__ __forceinline__ void body(const Frag& f, const float* el, const float* el2,
    int q, const sh8& ones, f32x4 acc[2][4], f32x4 accz[2])
{
  float er[8], er2[8];
  #pragma unroll
  for (int e = 0; e < 8; ++e){
    unsigned u = (e < 4) ? (unsigned)f.ee2[0][e] : (unsigned)f.ee2[1][e-4];
    er[e]  = __uint_as_float(u << 16);
    er2[e] = __uint_as_float(u & 0xFFFF0000u);
  }
  #pragma unroll
  for (int m = 0; m < 2; ++m){
    const unsigned sw = f.bw[m] >> (q*8);
    unsigned fi[4];
    #pragma unroll
    for (int p = 0; p < 4; ++p){
      float w0 = fmaxf(el[m]*er[2*p],   el2[m]*er2[2*p]);
      float w1 = fmaxf(el[m]*er[2*p+1], el2[m]*er2[2*p+1]);
      w0 = (sw & (1u << (2*p)))   ? w0 : 0.0f;
      w1 = (sw & (1u << (2*p+1))) ? w1 : 0.0f;
      // RTZ bf16x2 pack in one v_perm_b32 (z-MFMA sums the SAME truncated values,
      // so the truncation bias cancels in num/z)
      fi[p] = __builtin_amdgcn_perm(__float_as_uint(w1), __float_as_uint(w0), 0x07060302u);
    }
    union { sh8 s; unsigned u[4]; } fa;
    fa.u[0]=fi[0]; fa.u[1]=fi[1]; fa.u[2]=fi[2]; fa.u[3]=fi[3];
    #pragma unroll
    for (int d = 0; d < 4; ++d)
      acc[m][d] = __builtin_amdgcn_mfma_f32_16x16x32_bf16(fa.s, f.hf[d], acc[m][d], 0, 0, 0);
    accz[m] = __builtin_amdgcn_mfma_f32_16x16x32_bf16(fa.s, ones, accz[m], 0, 0, 0);
  }
}

// grid 1024: block b -> i-tile (b>>3)*64, jq = (b>>1)&3, i-half = b&1.
// 4 waves = 4 heads; each wave: rows i0 + half*32 + {0,16} + r0, one head, 2048 j.
__global__ __launch_bounds__(256, 4) void k_attn(
    const unsigned* __restrict__ bits32, const __hip_bfloat16* __restrict__ ht,
    const float* __restrict__ El, const float* __restrict__ El2,
    const unsigned* __restrict__ ee, float* __restrict__ part, float* __restrict__ zpart)
{
  const int b = blockIdx.x;
  const int iblk = b >> 3, jq = (b >> 1) & 3, half = b & 1;
  const int lane = threadIdx.x & 63;
  const int h = threadIdx.x >> 6;
  const int r0 = lane & 15, q = lane >> 4;
  const int i0 = iblk * 64;
  const int ib = i0 + half*32;                 // this wave's 32-row base
  const int jbase = jq * 2048;
  const int joff = jbase + q*8;

  float el[2], el2[2];
  const unsigned* bp[2];
  #pragma unroll
  for (int m = 0; m < 2; ++m){
    const int row = ib + m*16 + r0;
    el[m]  = El [h*N + row];
    el2[m] = El2[h*N + row];
    bp[m] = bits32 + (size_t)row*(N/32) + (jbase >> 5);
  }

  // ones B-frag: B[k][0] = 1.0 for all k -> z = row-sums land in C col 0
  union { sh8 s; int i[4]; } onef;
  {
    int v = (r0 == 0) ? 0x3F803F80 : 0;
    onef.i[0]=v; onef.i[1]=v; onef.i[2]=v; onef.i[3]=v;
  }

  f32x4 acc[2][4];
  f32x4 accz[2];
  #pragma unroll
  for (int m = 0; m < 2; ++m){
    accz[m] = (f32x4){0.f,0.f,0.f,0.f};
    #pragma unroll
    for (int d = 0; d < 4; ++d)
      acc[m][d] = (f32x4){0.f,0.f,0.f,0.f};
  }

  const unsigned* eeh = ee + h*N;
  const __hip_bfloat16* htb = ht + (size_t)(h*64 + r0)*N;

  Frag fA, fB;
  ld_frag(fA, 0, bp[0], bp[1], eeh, htb, joff);

  for (int t = 0; t < 64; t += 2){
    ld_frag(fB, t+1, bp[0], bp[1], eeh, htb, joff);
    body(fA, el, el2, q, onef.s, acc, accz);
    const int tn = (t+2 < 64) ? t+2 : 0;      // last prefetch harmless (unused)
    ld_frag(fA, tn, bp[0], bp[1], eeh, htb, joff);
    body(fB, el, el2, q, onef.s, acc, accz);
  }

  // z partials: col 0 of accz -> lanes with r0==0, row = q*4+reg
  if (r0 == 0){
    #pragma unroll
    for (int m = 0; m < 2; ++m)
      #pragma unroll
      for (int reg = 0; reg < 4; ++reg)
        zpart[(jq*4 + h)*N + ib + m*16 + q*4 + reg] = accz[m][reg];
  }

  // numerator partials: C layout col=r0, row=q*4+reg
  float* pp = part + (size_t)jq*N*HD + h*64 + r0;
  #pragma unroll
  for (int m = 0; m < 2; ++m)
    #pragma unroll
    for (int d = 0; d < 4; ++d)
      #pragma unroll
      for (int reg = 0; reg < 4; ++reg)
        pp[(size_t)(ib + m*16 + q*4 + reg)*HD + d*16] = acc[m][d][reg];
}

// ---------------- K3: combine 4 j-quarter partials, divide, write out --------------
__global__ void k_out(const float* __restrict__ part, const float* __restrict__ zpart,
                      float* __restrict__ out)
{
  const int t4 = (blockIdx.x*256 + threadIdx.x) * 4;   // 4 consecutive c (same head)
  const int i = t4 >> 8;
  const int h = (t4 & 255) >> 6;
  f32x4 a = *(const f32x4*)(part + t4);
  f32x4 bq = *(const f32x4*)(part + (size_t)N*HD + t4);
  f32x4 c = *(const f32x4*)(part + 2*(size_t)N*HD + t4);
  f32x4 d = *(const f32x4*)(part + 3*(size_t)N*HD + t4);
  float zz = zpart[h*N + i] + zpart[(4 + h)*N + i] + zpart[(8 + h)*N + i] + zpart[(12 + h)*N + i];
  f32x4 s = (a + bq + c + d) / zz;
  *(f32x4*)(out + t4) = s;
}

extern "C" void kernel_launch(void* const* d_in, const int* in_sizes, int n_in,
                              void* d_out, int out_size, void* d_ws, size_t ws_size,
                              hipStream_t stream) {
  const float* x   = (const float*)d_in[0];
  const int*   adj = (const int*)d_in[1];
  const float* W   = (const float*)d_in[2];
  const float* a_l = (const float*)d_in[3];
  const float* a_r = (const float*)d_in[4];
  float* out = (float*)d_out;

  char* ws = (char*)d_ws;
  __hip_bfloat16* Wt = (__hip_bfloat16*)ws;                     // 128 KB
  __hip_bfloat16* ht = (__hip_bfloat16*)(ws + 131072);          // 4 MB
  float*    El   = (float*)   (ws + 4325376);                   // 128 KB
  float*    El2  = (float*)   (ws + 4456448);                   // 128 KB
  unsigned* ee   = (unsigned*)(ws + 4587520);                   // 128 KB
  unsigned long long* bits = (unsigned long long*)(ws + 4718592); // 8 MB
  float*    part = (float*)   (ws + 13107200);                  // 32 MB
  float*    zpart= (float*)   (ws + 46661632);                  // 512 KB

  k_wt  <<<dim3(16,16), dim3(16,16), 0, stream>>>(W, Wt);
  k_h   <<<256, 256, 0, stream>>>(x, Wt, a_l, a_r, ht, El, El2, ee);
  k_bits<<<4096, 256, 0, stream>>>(adj, bits);
  k_attn<<<1024, 256, 0, stream>>>((const unsigned*)bits, ht, El, El2, ee, part, zpart);
  k_out <<<N*HD/1024, 256, 0, stream>>>(part, zpart, out);
}

// Round 4
// 510.391 us; speedup vs baseline: 1.1936x; 1.1936x over previous
//
#include <hip/hip_runtime.h>
#include <hip/hip_bf16.h>

#define N 8192
#define FIN 256
#define HD 256
#define LEAKY 0.2f

typedef short sh8 __attribute__((ext_vector_type(8)));   // bf16x8 MFMA fragment
typedef float f32x4 __attribute__((ext_vector_type(4)));
typedef int   i32x4 __attribute__((ext_vector_type(4)));

__device__ __forceinline__ int pack2bf(float a, float b){
  __hip_bfloat162 t = __float22bfloat162_rn(make_float2(a, b));
  union { __hip_bfloat162 h; int i; } u;
  u.h = t;
  return u.i;
}

__device__ __forceinline__ unsigned bf16hi_rne(float v){
  unsigned u = __float_as_uint(v);
  u += 0x7FFFu + ((u >> 16) & 1u);
  return u >> 16;
}

// ---------------- K0: W (256x256 f32, [k][c]) -> Wt (bf16, [c][k]) ----------------
__global__ void k_wt(const float* __restrict__ W, __hip_bfloat16* __restrict__ Wt){
  __shared__ float t[16][17];
  int tx = threadIdx.x, ty = threadIdx.y;
  int bx = blockIdx.x*16, by = blockIdx.y*16;
  t[ty][tx] = W[(by+ty)*HD + (bx+tx)];
  __syncthreads();
  Wt[(bx+ty)*FIN + (by+tx)] = __float2bfloat16(t[tx][ty]);
}

// ---------------- K1: h_t[c][n] = sum_k W[k][c] * x[n][k]  (bf16 out) --------------
// Fused epilogue: El=exp(sl), El2=exp(0.2*sl) (fp32, i-side) and EE[h][j] =
// packed (bf16(exp(sr)) | bf16(exp(0.2*sr))<<16) (j-side).
__global__ __launch_bounds__(256, 2) void k_h(
    const float* __restrict__ x, const __hip_bfloat16* __restrict__ Wt,
    const float* __restrict__ a_l, const float* __restrict__ a_r,
    __hip_bfloat16* __restrict__ ht, float* __restrict__ El, float* __restrict__ El2,
    unsigned* __restrict__ ee)
{
  const int lane = threadIdx.x & 63;
  const int w = threadIdx.x >> 6;      // c-group == head
  const int r0 = lane & 15, q = lane >> 4;
  const int c0 = w*64;
  const int n0 = blockIdx.x*32;

  f32x4 acc[4][2];
  #pragma unroll
  for (int m = 0; m < 4; ++m)
    #pragma unroll
    for (int nt = 0; nt < 2; ++nt)
      acc[m][nt] = (f32x4){0.f, 0.f, 0.f, 0.f};

  for (int kb = 0; kb < 8; ++kb){
    const int k = kb*32 + q*8;
    sh8 af[4];
    #pragma unroll
    for (int m = 0; m < 4; ++m)
      af[m] = *(const sh8*)(Wt + (c0 + m*16 + r0)*FIN + k);
    #pragma unroll
    for (int nt = 0; nt < 2; ++nt){
      const float* xp = x + (n0 + nt*16 + r0)*FIN + k;
      f32x4 xl = *(const f32x4*)xp;
      f32x4 xh = *(const f32x4*)(xp + 4);
      union { sh8 s; int i[4]; } bx;
      bx.i[0] = pack2bf(xl[0], xl[1]);
      bx.i[1] = pack2bf(xl[2], xl[3]);
      bx.i[2] = pack2bf(xh[0], xh[1]);
      bx.i[3] = pack2bf(xh[2], xh[3]);
      #pragma unroll
      for (int m = 0; m < 4; ++m)
        acc[m][nt] = __builtin_amdgcn_mfma_f32_16x16x32_bf16(af[m], bx.s, acc[m][nt], 0, 0, 0);
    }
  }

  float pl[2] = {0.f, 0.f}, pr[2] = {0.f, 0.f};
  #pragma unroll
  for (int m = 0; m < 4; ++m){
    #pragma unroll
    for (int reg = 0; reg < 4; ++reg){
      const int c = c0 + m*16 + q*4 + reg;      // C row = q*4+reg
      const float alv = a_l[c], arv = a_r[c];
      #pragma unroll
      for (int nt = 0; nt < 2; ++nt){
        float v = acc[m][nt][reg];
        ht[(size_t)c*N + (n0 + nt*16 + r0)] = __float2bfloat16(v);  // C col = r0
        pl[nt] += v*alv;
        pr[nt] += v*arv;
      }
    }
  }
  #pragma unroll
  for (int nt = 0; nt < 2; ++nt){
    pl[nt] += __shfl_xor(pl[nt], 16); pl[nt] += __shfl_xor(pl[nt], 32);
    pr[nt] += __shfl_xor(pr[nt], 16); pr[nt] += __shfl_xor(pr[nt], 32);
  }
  if (lane < 16){
    #pragma unroll
    for (int nt = 0; nt < 2; ++nt){
      const int n = n0 + nt*16 + r0;
      const float l = pl[nt], r = pr[nt];
      El [w*N + n] = __expf(l);
      El2[w*N + n] = __expf(LEAKY*l);
      float er  = __expf(r);
      float er2 = __expf(LEAKY*r);
      ee[w*N + n] = bf16hi_rne(er) | (bf16hi_rne(er2) << 16);
    }
  }
}

// ---------------- K_bits: adj (N*N int32) -> bitmask u64[row][N/64], eye OR'd in ---
__global__ __launch_bounds__(256) void k_bits(const int* __restrict__ adj,
                                              unsigned long long* __restrict__ bits)
{
  const int lane = threadIdx.x & 63;
  const int wid = (blockIdx.x*256 + threadIdx.x) >> 6;   // global wave id
  const int nw = (gridDim.x*256) >> 6;
  const int total = (N/64)*N;                            // row-major: idx = r*128 + c
  for (int idx = wid; idx < total; idx += nw){
    const int r = idx >> 7, c = idx & 127;
    int av = __builtin_nontemporal_load(adj + (size_t)r*N + c*64 + lane);
    unsigned long long b = __ballot(av != 0);
    if (c == (r >> 6)) b |= 1ull << (r & 63);            // + eye
    if (lane == 0) bits[idx] = b;
  }
}

// ---------------- K2: masked-softmax numerator/denominator partials ----------------
// Register pipeline payload: bits words + packed exp pairs for one j-tile.
struct Pf { unsigned bw0, bw1; i32x4 e0, e1; };

__device__ __forceinline__ void pf_load(Pf& p, int t,
    const unsigned* __restrict__ bp0, const unsigned* __restrict__ bp1,
    const unsigned* __restrict__ eeq)
{
  p.bw0 = bp0[t];
  p.bw1 = bp1[t];
  p.e0 = *(const i32x4*)(eeq + t*32);
  p.e1 = *(const i32x4*)(eeq + t*32 + 4);
}

__device__ __forceinline__ void body(const char* frp, int bufoff, const Pf& p,
    const float* el, const float* el2, int q, const sh8& ones,
    f32x4 acc[2][4], f32x4 accz[2])
{
  sh8 hf[4];
  #pragma unroll
  for (int d = 0; d < 4; ++d)
    hf[d] = *(const sh8*)(frp + bufoff + d*1024);   // ds_read_b128, imm offsets

  float er[8], er2[8];
  #pragma unroll
  for (int e = 0; e < 8; ++e){
    unsigned u = (e < 4) ? (unsigned)p.e0[e] : (unsigned)p.e1[e-4];
    er[e]  = __uint_as_float(u << 16);
    er2[e] = __uint_as_float(u & 0xFFFF0000u);
  }
  #pragma unroll
  for (int m = 0; m < 2; ++m){
    const unsigned sw = ((m == 0) ? p.bw0 : p.bw1) >> (q*8);
    unsigned fi[4];
    #pragma unroll
    for (int pp = 0; pp < 4; ++pp){
      float w0 = fmaxf(el[m]*er[2*pp],   el2[m]*er2[2*pp]);
      float w1 = fmaxf(el[m]*er[2*pp+1], el2[m]*er2[2*pp+1]);
      w0 = (sw & (1u << (2*pp)))   ? w0 : 0.0f;
      w1 = (sw & (1u << (2*pp+1))) ? w1 : 0.0f;
      // RTZ bf16x2 pack (z-MFMA sums the SAME truncated values -> bias cancels in num/z)
      fi[pp] = __builtin_amdgcn_perm(__float_as_uint(w1), __float_as_uint(w0), 0x07060302u);
    }
    union { sh8 s; unsigned u[4]; } fa;
    fa.u[0]=fi[0]; fa.u[1]=fi[1]; fa.u[2]=fi[2]; fa.u[3]=fi[3];
    #pragma unroll
    for (int d = 0; d < 4; ++d)
      acc[m][d] = __builtin_amdgcn_mfma_f32_16x16x32_bf16(fa.s, hf[d], acc[m][d], 0, 0, 0);
    accz[m] = __builtin_amdgcn_mfma_f32_16x16x32_bf16(fa.s, ones, accz[m], 0, 0, 0);
  }
}

// grid 1024: b -> head (b&3), j-quarter ((b>>2)&3), i-range 128 rows (b>>4).
// 4 waves, ALL same head; wave w owns rows i128*128 + w*32 + {0,16} + r0.
// ht j-tile (64 feat x 32 j = 4 KB) staged in LDS per iteration, shared by all waves.
__global__ __launch_bounds__(256, 4) void k_attn(
    const unsigned* __restrict__ bits32, const __hip_bfloat16* __restrict__ ht,
    const float* __restrict__ El, const float* __restrict__ El2,
    const unsigned* __restrict__ ee, float* __restrict__ part, float* __restrict__ zpart)
{
  __shared__ __align__(16) char smem[8192];     // 2 x 4 KB ht tile buffers
  const int b = blockIdx.x;
  const int h = b & 3, jq = (b >> 2) & 3, i128 = b >> 4;
  const int tid = threadIdx.x;
  const int lane = tid & 63;
  const int w = tid >> 6;
  const int r0 = lane & 15, q = lane >> 4;
  const int ib = i128*128 + w*32;               // this wave's 32-row base
  const int jbase = jq * 2048;

  // staging: thread tid fetches head-feature row (tid>>2), 16B chunk (tid&3)
  const __hip_bfloat16* gp = ht + (size_t)(h*64 + (tid >> 2))*N + jbase + (tid & 3)*8;
  char* lbase = smem + (w << 10);               // wave-uniform base; lane*16 implicit

  // per-wave fragment read base: row (d*16 + r0), byte col q*16
  const char* frp = smem + r0*64 + q*16;

  const float* el_ = El  + h*N + ib + r0;
  const float* el2_= El2 + h*N + ib + r0;
  float el[2]  = { el_[0],  el_[16]  };
  float el2[2] = { el2_[0], el2_[16] };
  const unsigned* bp0 = bits32 + (size_t)(ib + r0)*(N/32) + (jbase >> 5);
  const unsigned* bp1 = bp0 + 16*(N/32);
  const unsigned* eeq = ee + h*N + jbase + q*8;

  union { sh8 s; int i[4]; } onef;
  {
    int v = (r0 == 0) ? 0x3F803F80 : 0;
    onef.i[0]=v; onef.i[1]=v; onef.i[2]=v; onef.i[3]=v;
  }

  f32x4 acc[2][4];
  f32x4 accz[2];
  #pragma unroll
  for (int m = 0; m < 2; ++m){
    accz[m] = (f32x4){0.f,0.f,0.f,0.f};
    #pragma unroll
    for (int d = 0; d < 4; ++d)
      acc[m][d] = (f32x4){0.f,0.f,0.f,0.f};
  }

#define STAGE(buf, t) \
  __builtin_amdgcn_global_load_lds( \
      (const __attribute__((address_space(1))) void*)(gp + (t)*32), \
      (__attribute__((address_space(3))) void*)(lbase + (buf)*4096), 16, 0, 0)

  Pf pA, pB;
  STAGE(0, 0);
  pf_load(pA, 0, bp0, bp1, eeq);
  __syncthreads();                               // tile 0 resident in buf0

  for (int t = 0; t < 64; t += 2){
    STAGE(1, t+1);                               // async: tile t+1 -> buf1
    pf_load(pB, t+1, bp0, bp1, eeq);
    body(frp, 0, pA, el, el2, q, onef.s, acc, accz);
    __syncthreads();                             // buf1 ready; buf0 reads done
    const int t2 = (t+2 < 64) ? t+2 : 0;         // tail prefetch harmless
    STAGE(0, t2);
    pf_load(pA, t2, bp0, bp1, eeq);
    body(frp, 4096, pB, el, el2, q, onef.s, acc, accz);
    __syncthreads();
  }

  // z partials: col 0 of accz -> lanes with r0==0, row = q*4+reg
  if (r0 == 0){
    #pragma unroll
    for (int m = 0; m < 2; ++m)
      #pragma unroll
      for (int reg = 0; reg < 4; ++reg)
        zpart[(jq*4 + h)*N + ib + m*16 + q*4 + reg] = accz[m][reg];
  }

  // numerator partials: C layout col=r0, row=q*4+reg
  float* pp = part + (size_t)jq*N*HD + h*64 + r0;
  #pragma unroll
  for (int m = 0; m < 2; ++m)
    #pragma unroll
    for (int d = 0; d < 4; ++d)
      #pragma unroll
      for (int reg = 0; reg < 4; ++reg)
        pp[(size_t)(ib + m*16 + q*4 + reg)*HD + d*16] = acc[m][d][reg];
#undef STAGE
}

// ---------------- K3: combine 4 j-quarter partials, divide, write out --------------
__global__ void k_out(const float* __restrict__ part, const float* __restrict__ zpart,
                      float* __restrict__ out)
{
  const int t4 = (blockIdx.x*256 + threadIdx.x) * 4;   // 4 consecutive c (same head)
  const int i = t4 >> 8;
  const int h = (t4 & 255) >> 6;
  f32x4 a = *(const f32x4*)(part + t4);
  f32x4 bq = *(const f32x4*)(part + (size_t)N*HD + t4);
  f32x4 c = *(const f32x4*)(part + 2*(size_t)N*HD + t4);
  f32x4 d = *(const f32x4*)(part + 3*(size_t)N*HD + t4);
  float zz = zpart[h*N + i] + zpart[(4 + h)*N + i] + zpart[(8 + h)*N + i] + zpart[(12 + h)*N + i];
  f32x4 s = (a + bq + c + d) / zz;
  *(f32x4*)(out + t4) = s;
}

extern "C" void kernel_launch(void* const* d_in, const int* in_sizes, int n_in,
                              void* d_out, int out_size, void* d_ws, size_t ws_size,
                              hipStream_t stream) {
  const float* x   = (const float*)d_in[0];
  const int*   adj = (const int*)d_in[1];
  const float* W   = (const float*)d_in[2];
  const float* a_l = (const float*)d_in[3];
  const float* a_r = (const float*)d_in[4];
  float* out = (float*)d_out;

  char* ws = (char*)d_ws;
  __hip_bfloat16* Wt = (__hip_bfloat16*)ws;                     // 128 KB
  __hip_bfloat16* ht = (__hip_bfloat16*)(ws + 131072);          // 4 MB
  float*    El   = (float*)   (ws + 4325376);                   // 128 KB
  float*    El2  = (float*)   (ws + 4456448);                   // 128 KB
  unsigned* ee   = (unsigned*)(ws + 4587520);                   // 128 KB
  unsigned long long* bits = (unsigned long long*)(ws + 4718592); // 8 MB
  float*    part = (float*)   (ws + 13107200);                  // 32 MB
  float*    zpart= (float*)   (ws + 46661632);                  // 512 KB

  k_wt  <<<dim3(16,16), dim3(16,16), 0, stream>>>(W, Wt);
  k_h   <<<256, 256, 0, stream>>>(x, Wt, a_l, a_r, ht, El, El2, ee);
  k_bits<<<4096, 256, 0, stream>>>(adj, bits);
  k_attn<<<1024, 256, 0, stream>>>((const unsigned*)bits, ht, El, El2, ee, part, zpart);
  k_out <<<N*HD/1024, 256, 0, stream>>>(part, zpart, out);
}

// Round 5
// 492.189 us; speedup vs baseline: 1.2377x; 1.0370x over previous
//
#include <hip/hip_runtime.h>
#include <hip/hip_bf16.h>

#define N 8192
#define FIN 256
#define HD 256
#define LEAKY 0.2f

typedef short sh8 __attribute__((ext_vector_type(8)));   // bf16x8 MFMA fragment
typedef float f32x4 __attribute__((ext_vector_type(4)));
typedef int   i32x4 __attribute__((ext_vector_type(4)));

__device__ __forceinline__ int pack2bf(float a, float b){
  __hip_bfloat162 t = __float22bfloat162_rn(make_float2(a, b));
  union { __hip_bfloat162 h; int i; } u;
  u.h = t;
  return u.i;
}

// ---------------- K0: W (256x256 f32, [k][c]) -> Wt (bf16, [c][k]) ----------------
__global__ void k_wt(const float* __restrict__ W, __hip_bfloat16* __restrict__ Wt){
  __shared__ float t[16][17];
  int tx = threadIdx.x, ty = threadIdx.y;
  int bx = blockIdx.x*16, by = blockIdx.y*16;
  t[ty][tx] = W[(by+ty)*HD + (bx+tx)];
  __syncthreads();
  Wt[(bx+ty)*FIN + (by+tx)] = __float2bfloat16(t[tx][ty]);
}

// ---------------- K1: h_t[c][n] = sum_k W[k][c] * x[n][k]  (bf16 out) --------------
// Fused epilogue: El=exp(sl), El2=exp(0.2*sl), Er=exp(sr), Er2=exp(0.2*sr), all fp32.
__global__ __launch_bounds__(256, 2) void k_h(
    const float* __restrict__ x, const __hip_bfloat16* __restrict__ Wt,
    const float* __restrict__ a_l, const float* __restrict__ a_r,
    __hip_bfloat16* __restrict__ ht, float* __restrict__ El, float* __restrict__ El2,
    float* __restrict__ Er, float* __restrict__ Er2)
{
  const int lane = threadIdx.x & 63;
  const int w = threadIdx.x >> 6;      // c-group == head
  const int r0 = lane & 15, q = lane >> 4;
  const int c0 = w*64;
  const int n0 = blockIdx.x*32;

  f32x4 acc[4][2];
  #pragma unroll
  for (int m = 0; m < 4; ++m)
    #pragma unroll
    for (int nt = 0; nt < 2; ++nt)
      acc[m][nt] = (f32x4){0.f, 0.f, 0.f, 0.f};

  for (int kb = 0; kb < 8; ++kb){
    const int k = kb*32 + q*8;
    sh8 af[4];
    #pragma unroll
    for (int m = 0; m < 4; ++m)
      af[m] = *(const sh8*)(Wt + (c0 + m*16 + r0)*FIN + k);
    #pragma unroll
    for (int nt = 0; nt < 2; ++nt){
      const float* xp = x + (n0 + nt*16 + r0)*FIN + k;
      f32x4 xl = *(const f32x4*)xp;
      f32x4 xh = *(const f32x4*)(xp + 4);
      union { sh8 s; int i[4]; } bx;
      bx.i[0] = pack2bf(xl[0], xl[1]);
      bx.i[1] = pack2bf(xl[2], xl[3]);
      bx.i[2] = pack2bf(xh[0], xh[1]);
      bx.i[3] = pack2bf(xh[2], xh[3]);
      #pragma unroll
      for (int m = 0; m < 4; ++m)
        acc[m][nt] = __builtin_amdgcn_mfma_f32_16x16x32_bf16(af[m], bx.s, acc[m][nt], 0, 0, 0);
    }
  }

  float pl[2] = {0.f, 0.f}, pr[2] = {0.f, 0.f};
  #pragma unroll
  for (int m = 0; m < 4; ++m){
    #pragma unroll
    for (int reg = 0; reg < 4; ++reg){
      const int c = c0 + m*16 + q*4 + reg;      // C row = q*4+reg
      const float alv = a_l[c], arv = a_r[c];
      #pragma unroll
      for (int nt = 0; nt < 2; ++nt){
        float v = acc[m][nt][reg];
        ht[(size_t)c*N + (n0 + nt*16 + r0)] = __float2bfloat16(v);  // C col = r0
        pl[nt] += v*alv;
        pr[nt] += v*arv;
      }
    }
  }
  #pragma unroll
  for (int nt = 0; nt < 2; ++nt){
    pl[nt] += __shfl_xor(pl[nt], 16); pl[nt] += __shfl_xor(pl[nt], 32);
    pr[nt] += __shfl_xor(pr[nt], 16); pr[nt] += __shfl_xor(pr[nt], 32);
  }
  if (lane < 16){
    #pragma unroll
    for (int nt = 0; nt < 2; ++nt){
      const int n = n0 + nt*16 + r0;
      const float l = pl[nt], r = pr[nt];
      El [w*N + n] = __expf(l);
      El2[w*N + n] = __expf(LEAKY*l);
      Er [w*N + n] = __expf(r);
      Er2[w*N + n] = __expf(LEAKY*r);
    }
  }
}

// ---------------- K_bits: adj (N*N int32) -> bitmask u64[row][N/64], eye OR'd in ---
__global__ __launch_bounds__(256) void k_bits(const int* __restrict__ adj,
                                              unsigned long long* __restrict__ bits)
{
  const int lane = threadIdx.x & 63;
  const int wid = (blockIdx.x*256 + threadIdx.x) >> 6;   // global wave id
  const int nw = (gridDim.x*256) >> 6;
  const int total = (N/64)*N;                            // row-major: idx = r*128 + c
  for (int idx = wid; idx < total; idx += nw){
    const int r = idx >> 7, c = idx & 127;
    int av = __builtin_nontemporal_load(adj + (size_t)r*N + c*64 + lane);
    unsigned long long b = __ballot(av != 0);
    if (c == (r >> 6)) b |= 1ull << (r & 63);            // + eye
    if (lane == 0) bits[idx] = b;
  }
}

// ---------------- K2: masked-softmax numerator/denominator partials ----------------
// grid 1024: b -> head (b&3), j-quarter ((b>>2)&3), i-range 128 rows (b>>4).
// 4 waves, ALL same head; wave w owns rows i128*128 + w*32 + {0,16} + r0.
// 128-j tile (64 feat x 128 j bf16 = 16 KB) double-buffered in LDS; one barrier/tile.
// LDS layout: [ss:4][feat:64][j32: 64B] -> addr = ss*4096 + f*64 + jloc*2.
__global__ __launch_bounds__(256, 4) void k_attn(
    const unsigned* __restrict__ bits32, const __hip_bfloat16* __restrict__ ht,
    const float* __restrict__ El, const float* __restrict__ El2,
    const float* __restrict__ Er, const float* __restrict__ Er2,
    float* __restrict__ part, float* __restrict__ zpart)
{
  __shared__ __align__(16) char smem[32768];    // 2 x 16 KB tile buffers
  const int b = blockIdx.x;
  const int h = b & 3, jq = (b >> 2) & 3, i128 = b >> 4;
  const int tid = threadIdx.x;
  const int lane = tid & 63;
  const int w = tid >> 6;
  const int r0 = lane & 15, q = lane >> 4;
  const int ib = i128*128 + w*32;               // this wave's 32-row base
  const int jbase = jq * 2048;

  // staging: instruction s stages j-subtile s; thread -> feat f = w*16+(lane>>2),
  // j chunk (lane&3)*8. LDS dest = s*4096 + w*1024 + lane*16 (HW: base + lane*16).
  const __hip_bfloat16* gp = ht + (size_t)(h*64 + w*16 + (lane >> 2))*N
                                + jbase + (lane & 3)*8;
  char* lb = smem + w*1024;

  // per-wave fragment read base: (f = d*16+r0, jloc = q*8)
  const char* frp = smem + r0*64 + q*16;

  const float* el_ = El  + h*N + ib + r0;
  const float* el2_= El2 + h*N + ib + r0;
  const float el[2]  = { el_[0],  el_[16]  };
  const float el2[2] = { el2_[0], el2_[16] };
  const unsigned* bp0 = bits32 + (size_t)(ib + r0)*(N/32) + (jbase >> 5);
  const unsigned* bp1 = bp0 + 16*(N/32);
  const float* erq  = Er  + h*N + jbase + q*8;
  const float* er2q = Er2 + h*N + jbase + q*8;

  union { sh8 s; int i[4]; } onef;
  {
    int v = (r0 == 0) ? 0x3F803F80 : 0;
    onef.i[0]=v; onef.i[1]=v; onef.i[2]=v; onef.i[3]=v;
  }

  f32x4 acc[2][4];
  f32x4 accz[2];
  #pragma unroll
  for (int m = 0; m < 2; ++m){
    accz[m] = (f32x4){0.f,0.f,0.f,0.f};
    #pragma unroll
    for (int d = 0; d < 4; ++d)
      acc[m][d] = (f32x4){0.f,0.f,0.f,0.f};
  }

#define STAGE(bufoff, t) do { \
    const __hip_bfloat16* _g = gp + (t)*128; \
    _Pragma("unroll") \
    for (int _s = 0; _s < 4; ++_s) \
      __builtin_amdgcn_global_load_lds( \
        (const __attribute__((address_space(1))) void*)(_g + _s*32), \
        (__attribute__((address_space(3))) void*)(lb + (bufoff) + _s*4096), 16, 0, 0); \
  } while(0)

#define TILE(bufoff, t) do { \
    i32x4 bw0 = *(const i32x4*)(bp0 + (t)*4); \
    i32x4 bw1 = *(const i32x4*)(bp1 + (t)*4); \
    _Pragma("unroll") \
    for (int ss = 0; ss < 4; ++ss){ \
      const int jo = (t)*128 + ss*32; \
      f32x4 erl  = *(const f32x4*)(erq  + jo); \
      f32x4 erh  = *(const f32x4*)(erq  + jo + 4); \
      f32x4 e2l  = *(const f32x4*)(er2q + jo); \
      f32x4 e2h  = *(const f32x4*)(er2q + jo + 4); \
      float er_[8]  = {erl[0],erl[1],erl[2],erl[3],erh[0],erh[1],erh[2],erh[3]}; \
      float er2_[8] = {e2l[0],e2l[1],e2l[2],e2l[3],e2h[0],e2h[1],e2h[2],e2h[3]}; \
      sh8 hf[4]; \
      _Pragma("unroll") \
      for (int d = 0; d < 4; ++d) \
        hf[d] = *(const sh8*)(frp + (bufoff) + ss*4096 + d*1024); \
      _Pragma("unroll") \
      for (int m = 0; m < 2; ++m){ \
        const unsigned sw = ((unsigned)((m==0)?bw0[ss]:bw1[ss])) >> (q*8); \
        unsigned fi[4]; \
        _Pragma("unroll") \
        for (int p = 0; p < 4; ++p){ \
          float w0 = fmaxf(el[m]*er_[2*p],   el2[m]*er2_[2*p]); \
          float w1 = fmaxf(el[m]*er_[2*p+1], el2[m]*er2_[2*p+1]); \
          w0 = (sw & (1u << (2*p)))   ? w0 : 0.0f; \
          w1 = (sw & (1u << (2*p+1))) ? w1 : 0.0f; \
          fi[p] = __builtin_amdgcn_perm(__float_as_uint(w1), __float_as_uint(w0), 0x07060302u); \
        } \
        union { sh8 s; unsigned u[4]; } fa; \
        fa.u[0]=fi[0]; fa.u[1]=fi[1]; fa.u[2]=fi[2]; fa.u[3]=fi[3]; \
        _Pragma("unroll") \
        for (int d = 0; d < 4; ++d) \
          acc[m][d] = __builtin_amdgcn_mfma_f32_16x16x32_bf16(fa.s, hf[d], acc[m][d], 0, 0, 0); \
        accz[m] = __builtin_amdgcn_mfma_f32_16x16x32_bf16(fa.s, onef.s, accz[m], 0, 0, 0); \
      } \
    } \
  } while(0)

  STAGE(0, 0);
  __syncthreads();                               // tile 0 resident in buf0

  for (int t = 0; t < 16; t += 2){
    STAGE(16384, t+1);                           // async: tile t+1 -> buf1
    TILE(0, t);                                  // compute tile t from buf0
    __syncthreads();                             // buf1 staged; buf0 reads done
    const int t2 = (t+2 < 16) ? t+2 : 0;         // tail prefetch harmless
    STAGE(0, t2);
    TILE(16384, t+1);
    __syncthreads();
  }

  // z partials: col 0 of accz -> lanes with r0==0, row = q*4+reg
  if (r0 == 0){
    #pragma unroll
    for (int m = 0; m < 2; ++m)
      #pragma unroll
      for (int reg = 0; reg < 4; ++reg)
        zpart[(jq*4 + h)*N + ib + m*16 + q*4 + reg] = accz[m][reg];
  }

  // numerator partials: C layout col=r0, row=q*4+reg
  float* pp = part + (size_t)jq*N*HD + h*64 + r0;
  #pragma unroll
  for (int m = 0; m < 2; ++m)
    #pragma unroll
    for (int d = 0; d < 4; ++d)
      #pragma unroll
      for (int reg = 0; reg < 4; ++reg)
        pp[(size_t)(ib + m*16 + q*4 + reg)*HD + d*16] = acc[m][d][reg];
#undef STAGE
#undef TILE
}

// ---------------- K3: combine 4 j-quarter partials, divide, write out --------------
__global__ void k_out(const float* __restrict__ part, const float* __restrict__ zpart,
                      float* __restrict__ out)
{
  const int t4 = (blockIdx.x*256 + threadIdx.x) * 4;   // 4 consecutive c (same head)
  const int i = t4 >> 8;
  const int h = (t4 & 255) >> 6;
  f32x4 a = *(const f32x4*)(part + t4);
  f32x4 bq = *(const f32x4*)(part + (size_t)N*HD + t4);
  f32x4 c = *(const f32x4*)(part + 2*(size_t)N*HD + t4);
  f32x4 d = *(const f32x4*)(part + 3*(size_t)N*HD + t4);
  float zz = zpart[h*N + i] + zpart[(4 + h)*N + i] + zpart[(8 + h)*N + i] + zpart[(12 + h)*N + i];
  f32x4 s = (a + bq + c + d) / zz;
  *(f32x4*)(out + t4) = s;
}

extern "C" void kernel_launch(void* const* d_in, const int* in_sizes, int n_in,
                              void* d_out, int out_size, void* d_ws, size_t ws_size,
                              hipStream_t stream) {
  const float* x   = (const float*)d_in[0];
  const int*   adj = (const int*)d_in[1];
  const float* W   = (const float*)d_in[2];
  const float* a_l = (const float*)d_in[3];
  const float* a_r = (const float*)d_in[4];
  float* out = (float*)d_out;

  char* ws = (char*)d_ws;
  __hip_bfloat16* Wt = (__hip_bfloat16*)ws;                     // 128 KB
  __hip_bfloat16* ht = (__hip_bfloat16*)(ws + 131072);          // 4 MB
  float*    El   = (float*)   (ws + 4325376);                   // 128 KB
  float*    El2  = (float*)   (ws + 4456448);                   // 128 KB
  float*    Er   = (float*)   (ws + 4587520);                   // 128 KB
  float*    Er2  = (float*)   (ws + 4718592);                   // 128 KB
  unsigned long long* bits = (unsigned long long*)(ws + 4849664); // 8 MB
  float*    part = (float*)   (ws + 13238272);                  // 32 MB
  float*    zpart= (float*)   (ws + 46792704);                  // 512 KB

  k_wt  <<<dim3(16,16), dim3(16,16), 0, stream>>>(W, Wt);
  k_h   <<<256, 256, 0, stream>>>(x, Wt, a_l, a_r, ht, El, El2, Er, Er2);
  k_bits<<<4096, 256, 0, stream>>>(adj, bits);
  k_attn<<<1024, 256, 0, stream>>>((const unsigned*)bits, ht, El, El2, Er, Er2, part, zpart);
  k_out <<<N*HD/1024, 256, 0, stream>>>(part, zpart, out);
}

// Round 6
// 486.197 us; speedup vs baseline: 1.2529x; 1.0123x over previous
//
#include <hip/hip_runtime.h>
#include <hip/hip_bf16.h>

#define N 8192
#define FIN 256
#define HD 256
#define LEAKY 0.2f

typedef short sh8 __attribute__((ext_vector_type(8)));   // bf16x8 MFMA fragment
typedef float f32x4 __attribute__((ext_vector_type(4)));
typedef int   i32x4 __attribute__((ext_vector_type(4)));

__device__ __forceinline__ int pack2bf(float a, float b){
  __hip_bfloat162 t = __float22bfloat162_rn(make_float2(a, b));
  union { __hip_bfloat162 h; int i; } u;
  u.h = t;
  return u.i;
}

__device__ __forceinline__ unsigned bf16hi_rne(float v){
  unsigned u = __float_as_uint(v);
  u += 0x7FFFu + ((u >> 16) & 1u);
  return u >> 16;
}

// ---------------- K0: W (256x256 f32, [k][c]) -> Wt (bf16, [c][k]) ----------------
__global__ void k_wt(const float* __restrict__ W, __hip_bfloat16* __restrict__ Wt){
  __shared__ float t[16][17];
  int tx = threadIdx.x, ty = threadIdx.y;
  int bx = blockIdx.x*16, by = blockIdx.y*16;
  t[ty][tx] = W[(by+ty)*HD + (bx+tx)];
  __syncthreads();
  Wt[(bx+ty)*FIN + (by+tx)] = __float2bfloat16(t[tx][ty]);
}

// ---------------- K1: h_t[c][n] = sum_k W[k][c] * x[n][k]  (bf16 out) --------------
// Fused epilogue: El=exp(sl), El2=exp(0.2*sl) fp32 (i-side);
// ee[h][j] = bf16(exp(sr)) | bf16(exp(0.2*sr))<<16 (j-side, packed).
__global__ __launch_bounds__(256, 2) void k_h(
    const float* __restrict__ x, const __hip_bfloat16* __restrict__ Wt,
    const float* __restrict__ a_l, const float* __restrict__ a_r,
    __hip_bfloat16* __restrict__ ht, float* __restrict__ El, float* __restrict__ El2,
    unsigned* __restrict__ ee)
{
  const int lane = threadIdx.x & 63;
  const int w = threadIdx.x >> 6;      // c-group == head
  const int r0 = lane & 15, q = lane >> 4;
  const int c0 = w*64;
  const int n0 = blockIdx.x*32;

  f32x4 acc[4][2];
  #pragma unroll
  for (int m = 0; m < 4; ++m)
    #pragma unroll
    for (int nt = 0; nt < 2; ++nt)
      acc[m][nt] = (f32x4){0.f, 0.f, 0.f, 0.f};

  for (int kb = 0; kb < 8; ++kb){
    const int k = kb*32 + q*8;
    sh8 af[4];
    #pragma unroll
    for (int m = 0; m < 4; ++m)
      af[m] = *(const sh8*)(Wt + (c0 + m*16 + r0)*FIN + k);
    #pragma unroll
    for (int nt = 0; nt < 2; ++nt){
      const float* xp = x + (n0 + nt*16 + r0)*FIN + k;
      f32x4 xl = *(const f32x4*)xp;
      f32x4 xh = *(const f32x4*)(xp + 4);
      union { sh8 s; int i[4]; } bx;
      bx.i[0] = pack2bf(xl[0], xl[1]);
      bx.i[1] = pack2bf(xl[2], xl[3]);
      bx.i[2] = pack2bf(xh[0], xh[1]);
      bx.i[3] = pack2bf(xh[2], xh[3]);
      #pragma unroll
      for (int m = 0; m < 4; ++m)
        acc[m][nt] = __builtin_amdgcn_mfma_f32_16x16x32_bf16(af[m], bx.s, acc[m][nt], 0, 0, 0);
    }
  }

  float pl[2] = {0.f, 0.f}, pr[2] = {0.f, 0.f};
  #pragma unroll
  for (int m = 0; m < 4; ++m){
    #pragma unroll
    for (int reg = 0; reg < 4; ++reg){
      const int c = c0 + m*16 + q*4 + reg;      // C row = q*4+reg
      const float alv = a_l[c], arv = a_r[c];
      #pragma unroll
      for (int nt = 0; nt < 2; ++nt){
        float v = acc[m][nt][reg];
        ht[(size_t)c*N + (n0 + nt*16 + r0)] = __float2bfloat16(v);  // C col = r0
        pl[nt] += v*alv;
        pr[nt] += v*arv;
      }
    }
  }
  #pragma unroll
  for (int nt = 0; nt < 2; ++nt){
    pl[nt] += __shfl_xor(pl[nt], 16); pl[nt] += __shfl_xor(pl[nt], 32);
    pr[nt] += __shfl_xor(pr[nt], 16); pr[nt] += __shfl_xor(pr[nt], 32);
  }
  if (lane < 16){
    #pragma unroll
    for (int nt = 0; nt < 2; ++nt){
      const int n = n0 + nt*16 + r0;
      const float l = pl[nt], r = pr[nt];
      El [w*N + n] = __expf(l);
      El2[w*N + n] = __expf(LEAKY*l);
      float er  = __expf(r);
      float er2 = __expf(LEAKY*r);
      ee[w*N + n] = bf16hi_rne(er) | (bf16hi_rne(er2) << 16);
    }
  }
}

// ---------------- K_bits: adj (N*N int32) -> bitmask u64[row][N/64], eye OR'd in ---
__global__ __launch_bounds__(256) void k_bits(const int* __restrict__ adj,
                                              unsigned long long* __restrict__ bits)
{
  const int lane = threadIdx.x & 63;
  const int wid = (blockIdx.x*256 + threadIdx.x) >> 6;   // global wave id
  const int nw = (gridDim.x*256) >> 6;
  const int total = (N/64)*N;                            // row-major: idx = r*128 + c
  for (int idx = wid; idx < total; idx += nw){
    const int r = idx >> 7, c = idx & 127;
    int av = __builtin_nontemporal_load(adj + (size_t)r*N + c*64 + lane);
    unsigned long long b = __ballot(av != 0);
    if (c == (r >> 6)) b |= 1ull << (r & 63);            // + eye
    if (lane == 0) bits[idx] = b;
  }
}

// ---------------- K2: masked-softmax numerator/denominator partials ----------------
// grid 1024: b -> head (b&3), j-quarter ((b>>2)&3), i-range 128 rows (b>>4).
// 4 waves, ALL same head; wave w owns rows i128*128 + w*32 + {0,16} + r0.
// 128-j tile (64 feat x 128 j bf16 = 16 KB) double-buffered in LDS; one barrier/tile.
// Register software-pipeline: hf(ds) + ee(global) prefetched one subtile ahead;
// first subtile of next tile loaded immediately after the barrier; bits one tile ahead.
__device__ __forceinline__ void sub_compute(
    const sh8 hf[4], const i32x4 ee2[2], unsigned swm0, unsigned swm1,
    const float el[2], const float el2[2], int q, const sh8& ones,
    f32x4 acc[2][4], f32x4 accz[2])
{
  float er[8], er2[8];
  #pragma unroll
  for (int e = 0; e < 8; ++e){
    unsigned u = (e < 4) ? (unsigned)ee2[0][e] : (unsigned)ee2[1][e-4];
    er[e]  = __uint_as_float(u << 16);
    er2[e] = __uint_as_float(u & 0xFFFF0000u);
  }
  #pragma unroll
  for (int m = 0; m < 2; ++m){
    const unsigned sw = ((m == 0) ? swm0 : swm1) >> (q*8);
    unsigned fi[4];
    #pragma unroll
    for (int p = 0; p < 4; ++p){
      float w0 = fmaxf(el[m]*er[2*p],   el2[m]*er2[2*p]);
      float w1 = fmaxf(el[m]*er[2*p+1], el2[m]*er2[2*p+1]);
      w0 = (sw & (1u << (2*p)))   ? w0 : 0.0f;
      w1 = (sw & (1u << (2*p+1))) ? w1 : 0.0f;
      // RTZ bf16x2 pack (z-MFMA sums the SAME truncated values -> bias cancels in num/z)
      fi[p] = __builtin_amdgcn_perm(__float_as_uint(w1), __float_as_uint(w0), 0x07060302u);
    }
    union { sh8 s; unsigned u[4]; } fa;
    fa.u[0]=fi[0]; fa.u[1]=fi[1]; fa.u[2]=fi[2]; fa.u[3]=fi[3];
    #pragma unroll
    for (int d = 0; d < 4; ++d)
      acc[m][d] = __builtin_amdgcn_mfma_f32_16x16x32_bf16(fa.s, hf[d], acc[m][d], 0, 0, 0);
    accz[m] = __builtin_amdgcn_mfma_f32_16x16x32_bf16(fa.s, ones, accz[m], 0, 0, 0);
  }
}

__global__ __launch_bounds__(256, 4) void k_attn(
    const unsigned* __restrict__ bits32, const __hip_bfloat16* __restrict__ ht,
    const float* __restrict__ El, const float* __restrict__ El2,
    const unsigned* __restrict__ ee, float* __restrict__ part, float* __restrict__ zpart)
{
  __shared__ __align__(16) char smem[32768];    // 2 x 16 KB tile buffers
  const int b = blockIdx.x;
  const int h = b & 3, jq = (b >> 2) & 3, i128 = b >> 4;
  const int tid = threadIdx.x;
  const int lane = tid & 63;
  const int w = tid >> 6;
  const int r0 = lane & 15, q = lane >> 4;
  const int ib = i128*128 + w*32;               // this wave's 32-row base
  const int jbase = jq * 2048;

  // staging: thread -> feat f = w*16+(lane>>2), j chunk (lane&3)*8.
  // LDS dest = s*4096 + w*1024 + lane*16 (HW: wave-uniform base + lane*16).
  const __hip_bfloat16* gp = ht + (size_t)(h*64 + w*16 + (lane >> 2))*N
                                + jbase + (lane & 3)*8;
  char* lb = smem + w*1024;

  // per-wave fragment read base: (f = d*16+r0, jloc = q*8)
  const char* frp = smem + r0*64 + q*16;

  const float* el_ = El  + h*N + ib + r0;
  const float* el2_= El2 + h*N + ib + r0;
  const float el[2]  = { el_[0],  el_[16]  };
  const float el2[2] = { el2_[0], el2_[16] };
  const unsigned* bp0 = bits32 + (size_t)(ib + r0)*(N/32) + (jbase >> 5);
  const unsigned* bp1 = bp0 + 16*(N/32);
  const unsigned* eeq = ee + h*N + jbase + q*8;

  union { sh8 s; int i[4]; } onef;
  {
    int v = (r0 == 0) ? 0x3F803F80 : 0;
    onef.i[0]=v; onef.i[1]=v; onef.i[2]=v; onef.i[3]=v;
  }

  f32x4 acc[2][4];
  f32x4 accz[2];
  #pragma unroll
  for (int m = 0; m < 2; ++m){
    accz[m] = (f32x4){0.f,0.f,0.f,0.f};
    #pragma unroll
    for (int d = 0; d < 4; ++d)
      acc[m][d] = (f32x4){0.f,0.f,0.f,0.f};
  }

#define STAGE(bufoff, t) do { \
    const __hip_bfloat16* _g = gp + (t)*128; \
    _Pragma("unroll") \
    for (int _s = 0; _s < 4; ++_s) \
      __builtin_amdgcn_global_load_lds( \
        (const __attribute__((address_space(1))) void*)(_g + _s*32), \
        (__attribute__((address_space(3))) void*)(lb + (bufoff) + _s*4096), 16, 0, 0); \
  } while(0)

#define LD_HF(dst, bufoff, ss) do { \
    _Pragma("unroll") \
    for (int _d = 0; _d < 4; ++_d) \
      dst[_d] = *(const sh8*)(frp + (bufoff) + (ss)*4096 + _d*1024); \
  } while(0)

#define LD_EE(dst, t, ss) do { \
    dst[0] = *(const i32x4*)(eeq + (t)*128 + (ss)*32); \
    dst[1] = *(const i32x4*)(eeq + (t)*128 + (ss)*32 + 4); \
  } while(0)

  sh8   hfc[4], hfn[4];
  i32x4 eec[2], een[2];
  i32x4 bw0, bw1;

  STAGE(0, 0);
  __syncthreads();                               // tile 0 resident in buf0
  LD_HF(hfc, 0, 0);
  LD_EE(eec, 0, 0);
  bw0 = *(const i32x4*)(bp0);
  bw1 = *(const i32x4*)(bp1);

  for (int t = 0; t < 16; ++t){
    const int bo = (t & 1) ? 16384 : 0;
    const int bn = bo ^ 16384;
    const int tn = (t+1 < 16) ? t+1 : 0;         // tail wrap harmless
    STAGE(bn, tn);                               // async: next tile -> other buffer

    // subtiles 0..2 with one-ahead register prefetch
    #pragma unroll
    for (int ss = 0; ss < 3; ++ss){
      LD_HF(hfn, bo, ss+1);
      LD_EE(een, t, ss+1);
      sub_compute(hfc, eec, (unsigned)bw0[ss], (unsigned)bw1[ss],
                  el, el2, q, onef.s, acc, accz);
      #pragma unroll
      for (int d = 0; d < 4; ++d) hfc[d] = hfn[d];
      eec[0] = een[0]; eec[1] = een[1];
    }
    // prefetch next tile's bits during last subtile
    i32x4 nb0 = *(const i32x4*)(bp0 + tn*4);
    i32x4 nb1 = *(const i32x4*)(bp1 + tn*4);
    sub_compute(hfc, eec, (unsigned)bw0[3], (unsigned)bw1[3],
                el, el2, q, onef.s, acc, accz);
    __syncthreads();                             // next tile staged; this buf free
    LD_HF(hfc, bn, 0);                           // first subtile of next tile
    LD_EE(eec, tn, 0);
    bw0 = nb0; bw1 = nb1;
  }

  // z partials: col 0 of accz -> lanes with r0==0, row = q*4+reg
  if (r0 == 0){
    #pragma unroll
    for (int m = 0; m < 2; ++m)
      #pragma unroll
      for (int reg = 0; reg < 4; ++reg)
        zpart[(jq*4 + h)*N + ib + m*16 + q*4 + reg] = accz[m][reg];
  }

  // numerator partials: C layout col=r0, row=q*4+reg
  float* pp = part + (size_t)jq*N*HD + h*64 + r0;
  #pragma unroll
  for (int m = 0; m < 2; ++m)
    #pragma unroll
    for (int d = 0; d < 4; ++d)
      #pragma unroll
      for (int reg = 0; reg < 4; ++reg)
        pp[(size_t)(ib + m*16 + q*4 + reg)*HD + d*16] = acc[m][d][reg];
#undef STAGE
#undef LD_HF
#undef LD_EE
}

// ---------------- K3: combine 4 j-quarter partials, divide, write out --------------
__global__ void k_out(const float* __restrict__ part, const float* __restrict__ zpart,
                      float* __restrict__ out)
{
  const int t4 = (blockIdx.x*256 + threadIdx.x) * 4;   // 4 consecutive c (same head)
  const int i = t4 >> 8;
  const int h = (t4 & 255) >> 6;
  f32x4 a = *(const f32x4*)(part + t4);
  f32x4 bq = *(const f32x4*)(part + (size_t)N*HD + t4);
  f32x4 c = *(const f32x4*)(part + 2*(size_t)N*HD + t4);
  f32x4 d = *(const f32x4*)(part + 3*(size_t)N*HD + t4);
  float zz = zpart[h*N + i] + zpart[(4 + h)*N + i] + zpart[(8 + h)*N + i] + zpart[(12 + h)*N + i];
  f32x4 s = (a + bq + c + d) / zz;
  *(f32x4*)(out + t4) = s;
}

extern "C" void kernel_launch(void* const* d_in, const int* in_sizes, int n_in,
                              void* d_out, int out_size, void* d_ws, size_t ws_size,
                              hipStream_t stream) {
  const float* x   = (const float*)d_in[0];
  const int*   adj = (const int*)d_in[1];
  const float* W   = (const float*)d_in[2];
  const float* a_l = (const float*)d_in[3];
  const float* a_r = (const float*)d_in[4];
  float* out = (float*)d_out;

  char* ws = (char*)d_ws;
  __hip_bfloat16* Wt = (__hip_bfloat16*)ws;                     // 128 KB
  __hip_bfloat16* ht = (__hip_bfloat16*)(ws + 131072);          // 4 MB
  float*    El   = (float*)   (ws + 4325376);                   // 128 KB
  float*    El2  = (float*)   (ws + 4456448);                   // 128 KB
  unsigned* ee   = (unsigned*)(ws + 4587520);                   // 128 KB
  unsigned long long* bits = (unsigned long long*)(ws + 4718592); // 8 MB
  float*    part = (float*)   (ws + 13107200);                  // 32 MB
  float*    zpart= (float*)   (ws + 46661632);                  // 512 KB

  k_wt  <<<dim3(16,16), dim3(16,16), 0, stream>>>(W, Wt);
  k_h   <<<256, 256, 0, stream>>>(x, Wt, a_l, a_r, ht, El, El2, ee);
  k_bits<<<4096, 256, 0, stream>>>(adj, bits);
  k_attn<<<1024, 256, 0, stream>>>((const unsigned*)bits, ht, El, El2, ee, part, zpart);
  k_out <<<N*HD/1024, 256, 0, stream>>>(part, zpart, out);
}

// Round 7
// 485.900 us; speedup vs baseline: 1.2537x; 1.0006x over previous
//
#include <hip/hip_runtime.h>
#include <hip/hip_bf16.h>
#include <hip/hip_fp16.h>

#define N 8192
#define FIN 256
#define HD 256
#define LEAKY 0.2f

typedef short sh8 __attribute__((ext_vector_type(8)));       // bf16x8 MFMA fragment
typedef _Float16 h8 __attribute__((ext_vector_type(8)));     // f16x8 MFMA fragment
typedef _Float16 h2 __attribute__((ext_vector_type(2)));
typedef float f32x4 __attribute__((ext_vector_type(4)));
typedef int   i32x4 __attribute__((ext_vector_type(4)));

__device__ __forceinline__ int pack2bf(float a, float b){
  __hip_bfloat162 t = __float22bfloat162_rn(make_float2(a, b));
  union { __hip_bfloat162 h; int i; } u;
  u.h = t;
  return u.i;
}

__device__ __forceinline__ h2 u2h2(unsigned u){ union{unsigned u; h2 h;} c; c.u=u; return c.h; }
__device__ __forceinline__ unsigned h22u(h2 h){ union{unsigned u; h2 h;} c; c.h=h; return c.u; }

// ---------------- K0: W (256x256 f32, [k][c]) -> Wt (bf16, [c][k]) ----------------
__global__ void k_wt(const float* __restrict__ W, __hip_bfloat16* __restrict__ Wt){
  __shared__ float t[16][17];
  int tx = threadIdx.x, ty = threadIdx.y;
  int bx = blockIdx.x*16, by = blockIdx.y*16;
  t[ty][tx] = W[(by+ty)*HD + (bx+tx)];
  __syncthreads();
  Wt[(bx+ty)*FIN + (by+tx)] = __float2bfloat16(t[tx][ty]);
}

// ---------------- K1: h_t[c][n] (f16) + El/El2 fp32 + Erh/Er2h f16 ------------------
__global__ __launch_bounds__(256, 2) void k_h(
    const float* __restrict__ x, const __hip_bfloat16* __restrict__ Wt,
    const float* __restrict__ a_l, const float* __restrict__ a_r,
    _Float16* __restrict__ ht, float* __restrict__ El, float* __restrict__ El2,
    _Float16* __restrict__ Erh, _Float16* __restrict__ Er2h)
{
  const int lane = threadIdx.x & 63;
  const int w = threadIdx.x >> 6;      // c-group == head
  const int r0 = lane & 15, q = lane >> 4;
  const int c0 = w*64;
  const int n0 = blockIdx.x*32;

  f32x4 acc[4][2];
  #pragma unroll
  for (int m = 0; m < 4; ++m)
    #pragma unroll
    for (int nt = 0; nt < 2; ++nt)
      acc[m][nt] = (f32x4){0.f, 0.f, 0.f, 0.f};

  for (int kb = 0; kb < 8; ++kb){
    const int k = kb*32 + q*8;
    sh8 af[4];
    #pragma unroll
    for (int m = 0; m < 4; ++m)
      af[m] = *(const sh8*)(Wt + (c0 + m*16 + r0)*FIN + k);
    #pragma unroll
    for (int nt = 0; nt < 2; ++nt){
      const float* xp = x + (n0 + nt*16 + r0)*FIN + k;
      f32x4 xl = *(const f32x4*)xp;
      f32x4 xh = *(const f32x4*)(xp + 4);
      union { sh8 s; int i[4]; } bx;
      bx.i[0] = pack2bf(xl[0], xl[1]);
      bx.i[1] = pack2bf(xl[2], xl[3]);
      bx.i[2] = pack2bf(xh[0], xh[1]);
      bx.i[3] = pack2bf(xh[2], xh[3]);
      #pragma unroll
      for (int m = 0; m < 4; ++m)
        acc[m][nt] = __builtin_amdgcn_mfma_f32_16x16x32_bf16(af[m], bx.s, acc[m][nt], 0, 0, 0);
    }
  }

  float pl[2] = {0.f, 0.f}, pr[2] = {0.f, 0.f};
  #pragma unroll
  for (int m = 0; m < 4; ++m){
    #pragma unroll
    for (int reg = 0; reg < 4; ++reg){
      const int c = c0 + m*16 + q*4 + reg;      // C row = q*4+reg
      const float alv = a_l[c], arv = a_r[c];
      #pragma unroll
      for (int nt = 0; nt < 2; ++nt){
        float v = acc[m][nt][reg];
        ht[(size_t)c*N + (n0 + nt*16 + r0)] = (_Float16)v;  // C col = r0
        pl[nt] += v*alv;
        pr[nt] += v*arv;
      }
    }
  }
  #pragma unroll
  for (int nt = 0; nt < 2; ++nt){
    pl[nt] += __shfl_xor(pl[nt], 16); pl[nt] += __shfl_xor(pl[nt], 32);
    pr[nt] += __shfl_xor(pr[nt], 16); pr[nt] += __shfl_xor(pr[nt], 32);
  }
  if (lane < 16){
    #pragma unroll
    for (int nt = 0; nt < 2; ++nt){
      const int n = n0 + nt*16 + r0;
      const float l = pl[nt], r = pr[nt];
      El  [w*N + n] = __expf(l);
      El2 [w*N + n] = __expf(LEAKY*l);
      Erh [w*N + n] = (_Float16)__expf(r);
      Er2h[w*N + n] = (_Float16)__expf(LEAKY*r);
    }
  }
}

// ---------------- K_bits: adj (N*N int32) -> bitmask u64[row][N/64], eye OR'd in ---
__global__ __launch_bounds__(256) void k_bits(const int* __restrict__ adj,
                                              unsigned long long* __restrict__ bits)
{
  const int lane = threadIdx.x & 63;
  const int wid = (blockIdx.x*256 + threadIdx.x) >> 6;   // global wave id
  const int nw = (gridDim.x*256) >> 6;
  const int total = (N/64)*N;                            // row-major: idx = r*128 + c
  for (int idx = wid; idx < total; idx += nw){
    const int r = idx >> 7, c = idx & 127;
    int av = __builtin_nontemporal_load(adj + (size_t)r*N + c*64 + lane);
    unsigned long long b = __ballot(av != 0);
    if (c == (r >> 6)) b |= 1ull << (r & 63);            // + eye
    if (lane == 0) bits[idx] = b;
  }
}

// ---------------- K2: masked-softmax numerator/denominator partials ----------------
// grid 1024: b -> head (b&3), j-quarter ((b>>2)&3), i-range 128 rows (b>>4).
// 4 waves, ALL same head; wave w owns rows i128*128 + w*32 + {0,16} + r0.
// 128-j f16 tile (64 feat x 128 j = 16 KB) double-buffered in LDS; one barrier/tile.
// LDS bank-deconflict: global j-chunk (jc ^ ((f>>1)&3)) stored at slot jc, so each
// 8-lane read group covers all 8 bank-quads (was 4-way conflicted at stride f*64).
__device__ __forceinline__ void sub_compute(
    const char* frp, int loff, const _Float16* erq, const _Float16* er2q, int eoff,
    unsigned sw0, unsigned sw1, const h2 elh[2], const h2 el2h[2], int q,
    const h8& ones, f32x4 acc[2][4], f32x4 accz[2])
{
  h8 hf[4];
  #pragma unroll
  for (int d = 0; d < 4; ++d)
    hf[d] = *(const h8*)(frp + loff + d*1024);         // ds_read_b128

  i32x4 er4  = *(const i32x4*)(erq  + eoff);           // 4x h2: er pairs (j 2p,2p+1)
  i32x4 er24 = *(const i32x4*)(er2q + eoff);

  #pragma unroll
  for (int m = 0; m < 2; ++m){
    const unsigned sw = ((m == 0) ? sw0 : sw1) >> (q*8);
    unsigned fu[4];
    #pragma unroll
    for (int p = 0; p < 4; ++p){
      h2 w2 = __builtin_elementwise_max(elh[m]  * u2h2((unsigned)er4[p]),
                                        el2h[m] * u2h2((unsigned)er24[p]));
      unsigned wu = h22u(w2);
      const unsigned t = sw >> (2*p);
      wu = (t & 1u) ? wu : (wu & 0xFFFF0000u);         // zero low (j=2p) if masked
      wu = (t & 2u) ? wu : (wu & 0x0000FFFFu);         // zero high (j=2p+1) if masked
      fu[p] = wu;
    }
    union { h8 s; unsigned u[4]; } fa;
    fa.u[0]=fu[0]; fa.u[1]=fu[1]; fa.u[2]=fu[2]; fa.u[3]=fu[3];
    #pragma unroll
    for (int d = 0; d < 4; ++d)
      acc[m][d] = __builtin_amdgcn_mfma_f32_16x16x32_f16(fa.s, hf[d], acc[m][d], 0, 0, 0);
    accz[m] = __builtin_amdgcn_mfma_f32_16x16x32_f16(fa.s, ones, accz[m], 0, 0, 0);
  }
}

__global__ __launch_bounds__(256, 4) void k_attn(
    const unsigned* __restrict__ bits32, const _Float16* __restrict__ ht,
    const float* __restrict__ El, const float* __restrict__ El2,
    const _Float16* __restrict__ Erh, const _Float16* __restrict__ Er2h,
    float* __restrict__ part, float* __restrict__ zpart)
{
  __shared__ __align__(16) char smem[32768];    // 2 x 16 KB tile buffers
  const int b = blockIdx.x;
  const int h = b & 3, jq = (b >> 2) & 3, i128 = b >> 4;
  const int tid = threadIdx.x;
  const int lane = tid & 63;
  const int w = tid >> 6;
  const int r0 = lane & 15, q = lane >> 4;
  const int ib = i128*128 + w*32;               // this wave's 32-row base
  const int jbase = jq * 2048;

  // staging: thread -> feat f = w*16+(lane>>2); LDS slot (lane&3) gets global
  // j-chunk (lane&3)^((lane>>3)&3).  LDS dest = s*4096 + w*1024 + lane*16.
  const _Float16* gp = ht + (size_t)(h*64 + w*16 + (lane >> 2))*N
                          + jbase + (((lane & 3) ^ ((lane >> 3) & 3))*8);
  char* lb = smem + w*1024;

  // fragment read: (f = d*16+r0), slot q ^ ((r0>>1)&3)  -> global chunk q
  const char* frp = smem + r0*64 + ((q ^ ((r0 >> 1) & 3)) << 4);

  const float* el_ = El  + h*N + ib + r0;
  const float* el2_= El2 + h*N + ib + r0;
  h2 elh[2], el2h[2];
  #pragma unroll
  for (int m = 0; m < 2; ++m){
    _Float16 a = (_Float16)el_[m*16];
    _Float16 c = (_Float16)el2_[m*16];
    elh[m]  = (h2){a, a};
    el2h[m] = (h2){c, c};
  }
  const unsigned* bp0 = bits32 + (size_t)(ib + r0)*(N/32) + (jbase >> 5);
  const unsigned* bp1 = bp0 + 16*(N/32);
  const _Float16* erq  = Erh  + h*N + jbase + q*8;
  const _Float16* er2q = Er2h + h*N + jbase + q*8;

  union { h8 s; int i[4]; } onef;
  {
    int v = (r0 == 0) ? 0x3C003C00 : 0;          // f16 1.0 pair
    onef.i[0]=v; onef.i[1]=v; onef.i[2]=v; onef.i[3]=v;
  }

  f32x4 acc[2][4];
  f32x4 accz[2];
  #pragma unroll
  for (int m = 0; m < 2; ++m){
    accz[m] = (f32x4){0.f,0.f,0.f,0.f};
    #pragma unroll
    for (int d = 0; d < 4; ++d)
      acc[m][d] = (f32x4){0.f,0.f,0.f,0.f};
  }

#define STAGE(bufoff, t) do { \
    const _Float16* _g = gp + (t)*128; \
    _Pragma("unroll") \
    for (int _s = 0; _s < 4; ++_s) \
      __builtin_amdgcn_global_load_lds( \
        (const __attribute__((address_space(1))) void*)(_g + _s*32), \
        (__attribute__((address_space(3))) void*)(lb + (bufoff) + _s*4096), 16, 0, 0); \
  } while(0)

  STAGE(0, 0);
  __syncthreads();                               // tile 0 resident in buf0

  for (int t = 0; t < 16; ++t){
    const int bo = (t & 1) ? 16384 : 0;
    const int bn = bo ^ 16384;
    const int tn = (t + 1) & 15;                 // tail wrap harmless
    STAGE(bn, tn);                               // async: next tile -> other buffer

    i32x4 bw0 = *(const i32x4*)(bp0 + t*4);
    i32x4 bw1 = *(const i32x4*)(bp1 + t*4);
    #pragma unroll
    for (int ss = 0; ss < 4; ++ss)
      sub_compute(frp, bo + ss*4096, erq, er2q, t*128 + ss*32,
                  (unsigned)bw0[ss], (unsigned)bw1[ss],
                  elh, el2h, q, onef.s, acc, accz);

    __syncthreads();                             // next tile staged; this buf free
  }

  // z partials: col 0 of accz -> lanes with r0==0, row = q*4+reg
  if (r0 == 0){
    #pragma unroll
    for (int m = 0; m < 2; ++m)
      #pragma unroll
      for (int reg = 0; reg < 4; ++reg)
        zpart[(jq*4 + h)*N + ib + m*16 + q*4 + reg] = accz[m][reg];
  }

  // numerator partials: C layout col=r0, row=q*4+reg
  float* pp = part + (size_t)jq*N*HD + h*64 + r0;
  #pragma unroll
  for (int m = 0; m < 2; ++m)
    #pragma unroll
    for (int d = 0; d < 4; ++d)
      #pragma unroll
      for (int reg = 0; reg < 4; ++reg)
        pp[(size_t)(ib + m*16 + q*4 + reg)*HD + d*16] = acc[m][d][reg];
#undef STAGE
}

// ---------------- K3: combine 4 j-quarter partials, divide, write out --------------
__global__ void k_out(const float* __restrict__ part, const float* __restrict__ zpart,
                      float* __restrict__ out)
{
  const int t4 = (blockIdx.x*256 + threadIdx.x) * 4;   // 4 consecutive c (same head)
  const int i = t4 >> 8;
  const int h = (t4 & 255) >> 6;
  f32x4 a = *(const f32x4*)(part + t4);
  f32x4 bq = *(const f32x4*)(part + (size_t)N*HD + t4);
  f32x4 c = *(const f32x4*)(part + 2*(size_t)N*HD + t4);
  f32x4 d = *(const f32x4*)(part + 3*(size_t)N*HD + t4);
  float zz = zpart[h*N + i] + zpart[(4 + h)*N + i] + zpart[(8 + h)*N + i] + zpart[(12 + h)*N + i];
  f32x4 s = (a + bq + c + d) / zz;
  *(f32x4*)(out + t4) = s;
}

extern "C" void kernel_launch(void* const* d_in, const int* in_sizes, int n_in,
                              void* d_out, int out_size, void* d_ws, size_t ws_size,
                              hipStream_t stream) {
  const float* x   = (const float*)d_in[0];
  const int*   adj = (const int*)d_in[1];
  const float* W   = (const float*)d_in[2];
  const float* a_l = (const float*)d_in[3];
  const float* a_r = (const float*)d_in[4];
  float* out = (float*)d_out;

  char* ws = (char*)d_ws;
  __hip_bfloat16* Wt = (__hip_bfloat16*)ws;                     // 128 KB
  _Float16* ht   = (_Float16*)(ws + 131072);                    // 4 MB
  float*    El   = (float*)   (ws + 4325376);                   // 128 KB
  float*    El2  = (float*)   (ws + 4456448);                   // 128 KB
  _Float16* Erh  = (_Float16*)(ws + 4587520);                   // 64 KB
  _Float16* Er2h = (_Float16*)(ws + 4653056);                   // 64 KB
  unsigned long long* bits = (unsigned long long*)(ws + 4718592); // 8 MB
  float*    part = (float*)   (ws + 13107200);                  // 32 MB
  float*    zpart= (float*)   (ws + 46661632);                  // 512 KB

  k_wt  <<<dim3(16,16), dim3(16,16), 0, stream>>>(W, Wt);
  k_h   <<<256, 256, 0, stream>>>(x, Wt, a_l, a_r, ht, El, El2, Erh, Er2h);
  k_bits<<<4096, 256, 0, stream>>>(adj, bits);
  k_attn<<<1024, 256, 0, stream>>>((const unsigned*)bits, ht, El, El2, Erh, Er2h, part, zpart);
  k_out <<<N*HD/1024, 256, 0, stream>>>(part, zpart, out);
}